// Round 11
// baseline (131.344 us; speedup 1.0000x reference)
//
#include <hip/hip_runtime.h>
#include <hip/hip_bf16.h>

// Dims fixed by setup_inputs(): b=8, t=64, s=512, qu=vu=d=512.
#define B_  8
#define T_  64
#define S_  512
#define D_  512

#define QN (512 * 512)      // qproj elements (B*T x D)
#define KN (4096 * 512)     // kT elements (B x D x S)

#define TLOG2E 2.8853900817779268f   // 2*log2(e)
#define LOG2E  1.4426950408889634f

typedef __attribute__((ext_vector_type(8))) short bf16x8;
typedef __attribute__((ext_vector_type(4))) float f32x4;

// RNE f32x2 -> packed bf16x2 via v_cvt_pk_bf16_f32.
__device__ __forceinline__ unsigned int pk2(float a, float b) {
    float2 f; f.x = a; f.y = b;
    __hip_bfloat162 h = __float22bfloat162_rn(f);
    return *(unsigned int*)&h;
}

// ---------------------------------------------------------------------------
// bf16 MFMA projection GEMM, R11: 32x32 tiles, ONE WAVE per block, 2304
// blocks = 9 blocks/CU. Rationale: R8/R10 barrier restructures were both
// neutral -> gemm is latency-bound at 2.25 blocks/CU (serial per-CU block
// chains). Nine independent 1-wave pipelines per CU hide the vmcnt stalls;
// a 1-wave __syncthreads is just a waitcnt (no inter-wave coupling).
// K-order per dot product unchanged (BK=32 sequential) -> bit-identical acc.
//   blocks [0,2048):    kT[b][d][s] = (value @ W2)^T
//     x: bb = x&7 (XCD pin), r = x>>3: nt = r&15, mtl = r>>4; mt = bb*16+mtl
//   blocks [2048,2304):  qproj = query @ W1 row-major
//     r = x-2048: mt = r>>4, nt = r&15
// Epilogue: *TLOG2E; q adds (b1+b2) first.
// ---------------------------------------------------------------------------
__global__ __launch_bounds__(64) void mfma_gemm(
    const float* __restrict__ query, const float* __restrict__ value,
    const float* __restrict__ W1, const float* __restrict__ W2,
    const float* __restrict__ b1, const float* __restrict__ b2,
    float* __restrict__ qproj, float* __restrict__ kT)
{
    __shared__ __align__(16) unsigned short Ab[2][32][40];
    __shared__ __align__(16) unsigned short Bs[2][32][40];

    const int x = blockIdx.x;
    const float *A, *W;
    float* C;
    int mt, nt;
    bool isq;
    if (x < 2048) {
        const int bb = x & 7;
        const int r  = x >> 3;
        nt = r & 15;
        mt = bb * 16 + (r >> 4);
        A = value; W = W2; C = kT; isq = false;
    } else {
        const int r = x - 2048;
        mt = r >> 4; nt = r & 15;
        A = query; W = W1; C = qproj; isq = true;
    }

    const int tid = threadIdx.x;      // 0..63 (one wave)
    const int fm = tid & 15, fq = tid >> 4;

    f32x4 acc00 = {0.f, 0.f, 0.f, 0.f};
    f32x4 acc01 = acc00, acc10 = acc00, acc11 = acc00;

    // A staging: row ar = tid>>1 (0..31), k-cols ac..ac+15 (ac = (tid&1)*16)
    const int ar = tid >> 1;
    const int ac = (tid & 1) * 16;
    const float* Ag = A + (size_t)(mt * 32 + ar) * 512 + ac;
    // W staging: 4 k-rows k0r..k0r+3 (k0r = (tid>>3)*4), 4 n-cols n0..n0+3
    const int k0r = (tid >> 3) * 4;
    const int n0  = (tid & 7) * 4;
    const float* Wg = W + (size_t)k0r * 512 + nt * 32 + n0;

    float4 av0, av1, av2, av3;   // A row ar, k = ac..ac+15
    float4 wv0, wv1, wv2, wv3;   // W rows k0r..k0r+3 @ n0

#define LOADT(KOFF) do {                                                      \
        av0 = *(const float4*)(Ag + (KOFF));                                  \
        av1 = *(const float4*)(Ag + (KOFF) + 4);                              \
        av2 = *(const float4*)(Ag + (KOFF) + 8);                              \
        av3 = *(const float4*)(Ag + (KOFF) + 12);                             \
        wv0 = *(const float4*)(Wg + (size_t)(KOFF) * 512);                    \
        wv1 = *(const float4*)(Wg + (size_t)(KOFF) * 512 + 512);              \
        wv2 = *(const float4*)(Wg + (size_t)(KOFF) * 512 + 1024);             \
        wv3 = *(const float4*)(Wg + (size_t)(KOFF) * 512 + 1536);             \
    } while (0)

#define STAGE(BUF) do {                                                       \
        uint4 p0, p1;                                                         \
        p0.x = pk2(av0.x, av0.y); p0.y = pk2(av0.z, av0.w);                   \
        p0.z = pk2(av1.x, av1.y); p0.w = pk2(av1.z, av1.w);                   \
        p1.x = pk2(av2.x, av2.y); p1.y = pk2(av2.z, av2.w);                   \
        p1.z = pk2(av3.x, av3.y); p1.w = pk2(av3.z, av3.w);                   \
        *(uint4*)&Ab[BUF][ar][ac]     = p0;                                   \
        *(uint4*)&Ab[BUF][ar][ac + 8] = p1;                                   \
        *(unsigned int*)&Bs[BUF][n0 + 0][k0r]     = pk2(wv0.x, wv1.x);        \
        *(unsigned int*)&Bs[BUF][n0 + 1][k0r]     = pk2(wv0.y, wv1.y);        \
        *(unsigned int*)&Bs[BUF][n0 + 2][k0r]     = pk2(wv0.z, wv1.z);        \
        *(unsigned int*)&Bs[BUF][n0 + 3][k0r]     = pk2(wv0.w, wv1.w);        \
        *(unsigned int*)&Bs[BUF][n0 + 0][k0r + 2] = pk2(wv2.x, wv3.x);        \
        *(unsigned int*)&Bs[BUF][n0 + 1][k0r + 2] = pk2(wv2.y, wv3.y);        \
        *(unsigned int*)&Bs[BUF][n0 + 2][k0r + 2] = pk2(wv2.z, wv3.z);        \
        *(unsigned int*)&Bs[BUF][n0 + 3][k0r + 2] = pk2(wv2.w, wv3.w);        \
    } while (0)

    LOADT(0);
    STAGE(0);
    LOADT(32);
    __syncthreads();

    for (int i = 0; i < 16; ++i) {
        const int cur = i & 1, nxt = cur ^ 1;
        bf16x8 a0  = *(const bf16x8*)&Ab[cur][fm][fq * 8];
        bf16x8 a1  = *(const bf16x8*)&Ab[cur][16 + fm][fq * 8];
        bf16x8 b0  = *(const bf16x8*)&Bs[cur][fm][fq * 8];
        bf16x8 b1v = *(const bf16x8*)&Bs[cur][16 + fm][fq * 8];
        if (i < 15) {
            STAGE(nxt);                          // regs hold tile i+1
            const int kn = ((i + 2) & 15) * 32;  // prefetch tile i+2 (wrap)
            LOADT(kn);
        }
        acc00 = __builtin_amdgcn_mfma_f32_16x16x32_bf16(a0, b0,  acc00, 0, 0, 0);
        acc01 = __builtin_amdgcn_mfma_f32_16x16x32_bf16(a0, b1v, acc01, 0, 0, 0);
        acc10 = __builtin_amdgcn_mfma_f32_16x16x32_bf16(a1, b0,  acc10, 0, 0, 0);
        acc11 = __builtin_amdgcn_mfma_f32_16x16x32_bf16(a1, b1v, acc11, 0, 0, 0);
        __syncthreads();
    }
#undef STAGE
#undef LOADT

    // C/D layout (m89-verified): col = lane&15, row = fq*4 + reg.
    const int nA = nt * 32 + fm;          // first n (d)
    const int nB = nA + 16;
    const int m0 = mt * 32 + fq * 4;      // first m of acc*0 rows
    if (isq) {
        float biasA = b1[nA] + b2[nA];
        float biasB = b1[nB] + b2[nB];
#pragma unroll
        for (int r = 0; r < 4; ++r) {
            C[(size_t)(m0 + r) * 512 + nA]      = (acc00[r] + biasA) * TLOG2E;
            C[(size_t)(m0 + r) * 512 + nB]      = (acc01[r] + biasB) * TLOG2E;
            C[(size_t)(m0 + 16 + r) * 512 + nA] = (acc10[r] + biasA) * TLOG2E;
            C[(size_t)(m0 + 16 + r) * 512 + nB] = (acc11[r] + biasB) * TLOG2E;
        }
    } else {
        // kT[(bb*512 + d)*512 + s]; acc regs = 4 consecutive s at fixed d.
        const int bb = m0 >> 9;
        const int sl = m0 & 511;
        float* kb = C + (size_t)(bb * 512) * 512;
        float4 o;
        o.x = acc00[0] * TLOG2E; o.y = acc00[1] * TLOG2E;
        o.z = acc00[2] * TLOG2E; o.w = acc00[3] * TLOG2E;
        *(float4*)(kb + (size_t)nA * 512 + sl) = o;
        o.x = acc10[0] * TLOG2E; o.y = acc10[1] * TLOG2E;
        o.z = acc10[2] * TLOG2E; o.w = acc10[3] * TLOG2E;
        *(float4*)(kb + (size_t)nA * 512 + sl + 16) = o;
        o.x = acc01[0] * TLOG2E; o.y = acc01[1] * TLOG2E;
        o.z = acc01[2] * TLOG2E; o.w = acc01[3] * TLOG2E;
        *(float4*)(kb + (size_t)nB * 512 + sl) = o;
        o.x = acc11[0] * TLOG2E; o.y = acc11[1] * TLOG2E;
        o.z = acc11[2] * TLOG2E; o.w = acc11[3] * TLOG2E;
        *(float4*)(kb + (size_t)nB * 512 + sl + 16) = o;
    }
}

// ---------------------------------------------------------------------------
// Fused scores + softmax + context — BYTE-IDENTICAL to R9/R10 (control).
// ---------------------------------------------------------------------------
__global__ __launch_bounds__(1024) void fused_attn(
    const float* __restrict__ qproj, const float* __restrict__ kT,
    const int*   __restrict__ mask,  const float* __restrict__ scale,
    const float* __restrict__ value,
    float* __restrict__ ctx, float* __restrict__ attn)
{
    const int blk = blockIdx.x;
    const int b  = blk & 7;
    const int tp = blk >> 3;          // 0..31
    const size_t row0 = (size_t)(b * T_ + tp * 2);

    __shared__ __align__(16) float q0A[512];
    __shared__ __align__(16) float dA[512];
    __shared__ __align__(16) float cA[512];
    __shared__ __align__(16) float4 pex[4][256];   // (t0s0,t1s0,t0s1,t1s1)
    __shared__ __align__(16) float2 wp2[512];
    __shared__ __align__(16) float4 part[2][8][128];
    __shared__ float2 red2[16];

    const int tid  = threadIdx.x;     // 0..1023
    const int lane = tid & 63;
    const int wid  = tid >> 6;        // 0..15

    // ---- Phase 0: q0 / delta / scale into LDS ----
    if (tid < 512) {
        float q0v = qproj[row0 * D_ + tid];
        float q1v = qproj[(row0 + 1) * D_ + tid];
        q0A[tid] = q0v;
        dA[tid]  = __builtin_amdgcn_exp2f(q1v - q0v);   // delta_d
        cA[tid]  = scale[tid];
    }
    __syncthreads();

    // ---- Phase 1: thread (sp, dq) ----
    const int sp  = tid & 255;        // s-pair
    const int dq  = tid >> 8;         // d-quarter
    const int dlo = dq * 128;
    const float* kb = kT + ((size_t)(b * 512 + dlo)) * 512 + sp * 2;

    float p00 = 0.f, p10 = 0.f, p01 = 0.f, p11 = 0.f;

    float2 nf0 = *(const float2*)(kb);
    float2 nf1 = *(const float2*)(kb + 512);
    float2 nf2 = *(const float2*)(kb + 1024);
    float2 nf3 = *(const float2*)(kb + 1536);

#define SC2(KF, QV, DV, CV) do {                                              \
        float e0 = __builtin_amdgcn_exp2f((QV) + (KF).x);                     \
        float ra = __builtin_amdgcn_rcpf(e0 + 1.0f);                          \
        float rb = __builtin_amdgcn_rcpf(fmaf(e0, (DV), 1.0f));               \
        p00 = fmaf((CV), ra, p00); p10 = fmaf((CV), rb, p10);                 \
        float e1 = __builtin_amdgcn_exp2f((QV) + (KF).y);                     \
        float rc = __builtin_amdgcn_rcpf(e1 + 1.0f);                          \
        float rd = __builtin_amdgcn_rcpf(fmaf(e1, (DV), 1.0f));               \
        p01 = fmaf((CV), rc, p01); p11 = fmaf((CV), rd, p11);                 \
    } while (0)

    for (int g = 0; g < 32; ++g) {
        float2 kf0 = nf0, kf1 = nf1, kf2 = nf2, kf3 = nf3;
        const float* nb = kb + (size_t)(((g + 1) & 31) * 4) * 512;  // wrap
        nf0 = *(const float2*)(nb);
        nf1 = *(const float2*)(nb + 512);
        nf2 = *(const float2*)(nb + 1024);
        nf3 = *(const float2*)(nb + 1536);
        const int d0 = dlo + g * 4;
        float4 q4 = *(const float4*)&q0A[d0];
        float4 dl = *(const float4*)&dA[d0];
        float4 c4 = *(const float4*)&cA[d0];
        SC2(kf0, q4.x, dl.x, c4.x);
        SC2(kf1, q4.y, dl.y, c4.y);
        SC2(kf2, q4.z, dl.z, c4.z);
        SC2(kf3, q4.w, dl.w, c4.w);
    }
#undef SC2

    {
        float4 pq; pq.x = p00; pq.y = p10; pq.z = p01; pq.w = p11;
        pex[dq][sp] = pq;
    }
    __syncthreads();

    // ---- Phase 2: softmax over 512 s (waves 0-7), barriers block-wide ----
    float x0 = 0.f, x1 = 0.f;
    if (tid < 512) {
        const int s = tid;
        const int s2 = s >> 1;
        const bool odd = (s & 1) != 0;
        float4 r0 = pex[0][s2], r1 = pex[1][s2];
        float4 r2 = pex[2][s2], r3 = pex[3][s2];
        float pt0 = odd ? ((r0.z + r1.z) + (r2.z + r3.z))
                        : ((r0.x + r1.x) + (r2.x + r3.x));
        float pt1 = odd ? ((r0.w + r1.w) + (r2.w + r3.w))
                        : ((r0.y + r1.y) + (r2.y + r3.y));
        const int m = mask[b * S_ + s];
        x0 = m ? (-2.0f * pt0) : -1e9f;
        x1 = m ? (-2.0f * pt1) : -1e9f;
        float2 mx; mx.x = x0; mx.y = x1;
#pragma unroll
        for (int off = 32; off >= 1; off >>= 1) {
            mx.x = fmaxf(mx.x, __shfl_xor(mx.x, off));
            mx.y = fmaxf(mx.y, __shfl_xor(mx.y, off));
        }
        if (lane == 0) red2[wid] = mx;
    }
    __syncthreads();

    float e0 = 0.f, e1 = 0.f;
    if (tid < 512) {
        float2 M = red2[0];
#pragma unroll
        for (int i = 1; i < 8; ++i) {
            M.x = fmaxf(M.x, red2[i].x);
            M.y = fmaxf(M.y, red2[i].y);
        }
        e0 = __builtin_amdgcn_exp2f((x0 - M.x) * LOG2E);
        e1 = __builtin_amdgcn_exp2f((x1 - M.y) * LOG2E);
        float2 sm; sm.x = e0; sm.y = e1;
#pragma unroll
        for (int off = 32; off >= 1; off >>= 1) {
            sm.x += __shfl_xor(sm.x, off);
            sm.y += __shfl_xor(sm.y, off);
        }
        if (lane == 0) red2[8 + wid] = sm;
    }
    __syncthreads();

    if (tid < 512) {
        const int s = tid;
        float2 SS = red2[8];
#pragma unroll
        for (int i = 9; i < 16; ++i) {
            SS.x += red2[i].x;
            SS.y += red2[i].y;
        }
        const float w0 = e0 * __builtin_amdgcn_rcpf(SS.x);
        const float w1 = e1 * __builtin_amdgcn_rcpf(SS.y);
        float2 wpair; wpair.x = w0; wpair.y = w1;
        wp2[s] = wpair;
        attn[row0 * S_ + s]       = w0;
        attn[(row0 + 1) * S_ + s] = w1;
    }
    __syncthreads();

    // ---- Phase 3: context, all 16 waves ----
    const int g  = tid >> 7;          // s-group 0..7 (64 s each)
    const int v4 = tid & 127;
    const float* vb = value + ((size_t)(b * S_) + g * 64) * D_ + v4 * 4;
    float4 a0; a0.x = 0.f; a0.y = 0.f; a0.z = 0.f; a0.w = 0.f;
    float4 a1 = a0;
#pragma unroll 4
    for (int i = 0; i < 64; ++i) {
        float4 vv = *(const float4*)(vb + (size_t)i * D_);
        float2 w = wp2[g * 64 + i];
        a0.x = fmaf(w.x, vv.x, a0.x); a0.y = fmaf(w.x, vv.y, a0.y);
        a0.z = fmaf(w.x, vv.z, a0.z); a0.w = fmaf(w.x, vv.w, a0.w);
        a1.x = fmaf(w.y, vv.x, a1.x); a1.y = fmaf(w.y, vv.y, a1.y);
        a1.z = fmaf(w.y, vv.z, a1.z); a1.w = fmaf(w.y, vv.w, a1.w);
    }
    part[0][g][v4] = a0;
    part[1][g][v4] = a1;
    __syncthreads();
    if (tid < 256) {
        const int t = tid >> 7, v = tid & 127;
        float4 o; o.x = 0.f; o.y = 0.f; o.z = 0.f; o.w = 0.f;
#pragma unroll
        for (int gg = 0; gg < 8; ++gg) {
            float4 p = part[t][gg][v];
            o.x += p.x; o.y += p.y; o.z += p.z; o.w += p.w;
        }
        *(float4*)(ctx + (row0 + t) * D_ + v * 4) = o;
    }
}

extern "C" void kernel_launch(void* const* d_in, const int* in_sizes, int n_in,
                              void* d_out, int out_size, void* d_ws, size_t ws_size,
                              hipStream_t stream) {
    const float* query = (const float*)d_in[0];
    const float* value = (const float*)d_in[1];
    const int*   mask  = (const int*)  d_in[2];
    const float* W1w   = (const float*)d_in[3];
    const float* W1b   = (const float*)d_in[4];
    const float* W2w   = (const float*)d_in[5];
    const float* W2b   = (const float*)d_in[6];
    const float* scale = (const float*)d_in[7];

    float* ctx  = (float*)d_out;
    float* attn = (float*)d_out + (size_t)B_ * T_ * D_;

    float* qproj = (float*)d_ws;              // QN f32 (1 MB)
    float* kT    = qproj + (size_t)QN;        // KN f32 (8 MB), [b][d][s]

    mfma_gemm<<<2304, 64, 0, stream>>>(query, value, W1w, W2w, W1b, W2b,
                                       qproj, kT);
    fused_attn<<<256, 1024, 0, stream>>>(qproj, kT, mask, scale, value,
                                         ctx, attn);
}

// Round 14
// 126.318 us; speedup vs baseline: 1.0398x; 1.0398x over previous
//
#include <hip/hip_runtime.h>
#include <hip/hip_bf16.h>

// Dims fixed by setup_inputs(): b=8, t=64, s=512, qu=vu=d=512.
#define B_  8
#define T_  64
#define S_  512
#define D_  512

#define QN (512 * 512)      // qproj elements (B*T x D)
#define KN (4096 * 512)     // kT elements (B x D x S)

#define TLOG2E 2.8853900817779268f   // 2*log2(e)
#define LOG2E  1.4426950408889634f

typedef __attribute__((ext_vector_type(8))) short bf16x8;
typedef __attribute__((ext_vector_type(4))) float f32x4;

// RNE f32x2 -> packed bf16x2 via v_cvt_pk_bf16_f32.
__device__ __forceinline__ unsigned int pk2(float a, float b) {
    float2 f; f.x = a; f.y = b;
    __hip_bfloat162 h = __float22bfloat162_rn(f);
    return *(unsigned int*)&h;
}
// packed bf16x2 -> two f32 (bit-shift, exact)
#define BF2X(U) __uint_as_float((U) << 16)
#define BF2Y(U) __uint_as_float((U) & 0xffff0000u)

// ---------------------------------------------------------------------------
// bf16 MFMA projection GEMM (R10 576x256 BK=64 dbuf shape — best measured;
// R8/R10/R11 all neutral => gemm ~10-15 us, not the lever).
// R12 change (third submission; two broker-level infra failures, zero kernel
// signal): k-branch epilogue stores kT[b][d][s] as BF16 (halves the
// consumer's phase-1 L2 traffic, 256->128 MB). q-path stays f32 (tiny).
//   blocks [0,512):   kT = (value @ W2)^T, bf16
//   blocks [512,576): qproj = query @ W1 row-major, f32
// Epilogue: *TLOG2E; q adds (b1+b2) first.
// ---------------------------------------------------------------------------
__global__ __launch_bounds__(256) void mfma_gemm(
    const float* __restrict__ query, const float* __restrict__ value,
    const float* __restrict__ W1, const float* __restrict__ W2,
    const float* __restrict__ b1, const float* __restrict__ b2,
    float* __restrict__ qproj, unsigned short* __restrict__ kTb)
{
    __shared__ __align__(16) unsigned short Ab[2][64][72];
    __shared__ __align__(16) unsigned short Bs[2][64][72];

    const int x = blockIdx.x;
    const float *A, *W;
    int tm, tn;
    bool isq;
    if (x < 512) {
        tm = (x & 7) * 8 + ((x >> 3) & 7);
        tn = x >> 6;
        A = value; W = W2; isq = false;
    } else {
        int r = x - 512;
        tm = r >> 3; tn = r & 7;
        A = query; W = W1; isq = true;
    }

    const int tid  = threadIdx.x;
    const int lane = tid & 63;
    const int wid  = tid >> 6;
    const int wm = (wid & 1) * 32, wn = (wid >> 1) * 32;
    const int fm = lane & 15, fq = lane >> 4;

    f32x4 acc00 = {0.f, 0.f, 0.f, 0.f};
    f32x4 acc01 = acc00, acc10 = acc00, acc11 = acc00;

    const int ar = tid >> 2;
    const int kc = (tid & 3) * 16;
    const float* Ag = A + (size_t)(tm * 64 + ar) * 512 + kc;
    const int c0 = (tid & 15) * 4;
    const int kp = (tid >> 4) * 2;
    const float* Wg = W + (size_t)kp * 512 + tn * 64 + c0;

    float4 av0, av1, av2, av3;
    float4 wv0, wv1, wv2, wv3;

#define LOADT(KOFF) do {                                                      \
        av0 = *(const float4*)(Ag + (KOFF));                                  \
        av1 = *(const float4*)(Ag + (KOFF) + 4);                              \
        av2 = *(const float4*)(Ag + (KOFF) + 8);                              \
        av3 = *(const float4*)(Ag + (KOFF) + 12);                             \
        wv0 = *(const float4*)(Wg + (size_t)(KOFF) * 512);                    \
        wv1 = *(const float4*)(Wg + (size_t)(KOFF) * 512 + 512);              \
        wv2 = *(const float4*)(Wg + (size_t)((KOFF) + 32) * 512);             \
        wv3 = *(const float4*)(Wg + (size_t)((KOFF) + 32) * 512 + 512);       \
    } while (0)

#define STAGE(BUF) do {                                                       \
        uint4 p0, p1;                                                         \
        p0.x = pk2(av0.x, av0.y); p0.y = pk2(av0.z, av0.w);                   \
        p0.z = pk2(av1.x, av1.y); p0.w = pk2(av1.z, av1.w);                   \
        p1.x = pk2(av2.x, av2.y); p1.y = pk2(av2.z, av2.w);                   \
        p1.z = pk2(av3.x, av3.y); p1.w = pk2(av3.z, av3.w);                   \
        *(uint4*)&Ab[BUF][ar][kc]     = p0;                                   \
        *(uint4*)&Ab[BUF][ar][kc + 8] = p1;                                   \
        *(unsigned int*)&Bs[BUF][c0 + 0][kp]      = pk2(wv0.x, wv1.x);        \
        *(unsigned int*)&Bs[BUF][c0 + 1][kp]      = pk2(wv0.y, wv1.y);        \
        *(unsigned int*)&Bs[BUF][c0 + 2][kp]      = pk2(wv0.z, wv1.z);        \
        *(unsigned int*)&Bs[BUF][c0 + 3][kp]      = pk2(wv0.w, wv1.w);        \
        *(unsigned int*)&Bs[BUF][c0 + 0][kp + 32] = pk2(wv2.x, wv3.x);        \
        *(unsigned int*)&Bs[BUF][c0 + 1][kp + 32] = pk2(wv2.y, wv3.y);        \
        *(unsigned int*)&Bs[BUF][c0 + 2][kp + 32] = pk2(wv2.z, wv3.z);        \
        *(unsigned int*)&Bs[BUF][c0 + 3][kp + 32] = pk2(wv2.w, wv3.w);        \
    } while (0)

    LOADT(0);
    STAGE(0);
    LOADT(64);
    __syncthreads();

    for (int i = 0; i < 8; ++i) {
        const int cur = i & 1, nxt = cur ^ 1;
        bf16x8 a0, a1, b0, b1v;
#pragma unroll
        for (int kk = 0; kk < 64; kk += 32) {
            a0  = *(const bf16x8*)&Ab[cur][wm + fm][kk + fq * 8];
            a1  = *(const bf16x8*)&Ab[cur][wm + 16 + fm][kk + fq * 8];
            b0  = *(const bf16x8*)&Bs[cur][wn + fm][kk + fq * 8];
            b1v = *(const bf16x8*)&Bs[cur][wn + 16 + fm][kk + fq * 8];
            acc00 = __builtin_amdgcn_mfma_f32_16x16x32_bf16(a0, b0,  acc00, 0, 0, 0);
            acc01 = __builtin_amdgcn_mfma_f32_16x16x32_bf16(a0, b1v, acc01, 0, 0, 0);
            acc10 = __builtin_amdgcn_mfma_f32_16x16x32_bf16(a1, b0,  acc10, 0, 0, 0);
            acc11 = __builtin_amdgcn_mfma_f32_16x16x32_bf16(a1, b1v, acc11, 0, 0, 0);
        }
        if (i < 7) {
            STAGE(nxt);
            const int kn = ((i + 2) & 7) * 64;
            LOADT(kn);
        }
        __syncthreads();
    }
#undef STAGE
#undef LOADT

    // C/D layout (m89-verified): col = lane&15, row = fq*4 + reg.
    const int n0 = tn * 64 + wn + fm;
    const int n1 = n0 + 16;
    const int m0 = tm * 64 + wm + fq * 4;
    if (isq) {
        float bias0 = b1[n0] + b2[n0];
        float bias1 = b1[n1] + b2[n1];
#pragma unroll
        for (int r = 0; r < 4; ++r) {
            qproj[(size_t)(m0 + r) * 512 + n0]      = (acc00[r] + bias0) * TLOG2E;
            qproj[(size_t)(m0 + r) * 512 + n1]      = (acc01[r] + bias1) * TLOG2E;
            qproj[(size_t)(m0 + 16 + r) * 512 + n0] = (acc10[r] + bias0) * TLOG2E;
            qproj[(size_t)(m0 + 16 + r) * 512 + n1] = (acc11[r] + bias1) * TLOG2E;
        }
    } else {
        // kTb[(bb*512 + d)*512 + s] bf16; acc regs = 4 consecutive s at d.
        const int bb = m0 >> 9;
        const int sl = m0 & 511;
        unsigned short* kb = kTb + (size_t)(bb * 512) * 512;
        uint2 o;
        o.x = pk2(acc00[0] * TLOG2E, acc00[1] * TLOG2E);
        o.y = pk2(acc00[2] * TLOG2E, acc00[3] * TLOG2E);
        *(uint2*)(kb + (size_t)n0 * 512 + sl) = o;
        o.x = pk2(acc10[0] * TLOG2E, acc10[1] * TLOG2E);
        o.y = pk2(acc10[2] * TLOG2E, acc10[3] * TLOG2E);
        *(uint2*)(kb + (size_t)n0 * 512 + sl + 16) = o;
        o.x = pk2(acc01[0] * TLOG2E, acc01[1] * TLOG2E);
        o.y = pk2(acc01[2] * TLOG2E, acc01[3] * TLOG2E);
        *(uint2*)(kb + (size_t)n1 * 512 + sl) = o;
        o.x = pk2(acc11[0] * TLOG2E, acc11[1] * TLOG2E);
        o.y = pk2(acc11[2] * TLOG2E, acc11[3] * TLOG2E);
        *(uint2*)(kb + (size_t)n1 * 512 + sl + 16) = o;
    }
}

// ---------------------------------------------------------------------------
// Fused scores + softmax + context (R9 structure). ONLY change vs R11: phase
// 1 reads bf16 kT (4 B packed pair per lane -> 4 lines/wave-load, half L2
// bytes).
// ---------------------------------------------------------------------------
__global__ __launch_bounds__(1024) void fused_attn(
    const float* __restrict__ qproj, const unsigned short* __restrict__ kTb,
    const int*   __restrict__ mask,  const float* __restrict__ scale,
    const float* __restrict__ value,
    float* __restrict__ ctx, float* __restrict__ attn)
{
    const int blk = blockIdx.x;
    const int b  = blk & 7;
    const int tp = blk >> 3;          // 0..31
    const size_t row0 = (size_t)(b * T_ + tp * 2);

    __shared__ __align__(16) float q0A[512];
    __shared__ __align__(16) float dA[512];
    __shared__ __align__(16) float cA[512];
    __shared__ __align__(16) float4 pex[4][256];   // (t0s0,t1s0,t0s1,t1s1)
    __shared__ __align__(16) float2 wp2[512];
    __shared__ __align__(16) float4 part[2][8][128];
    __shared__ float2 red2[16];

    const int tid  = threadIdx.x;     // 0..1023
    const int lane = tid & 63;
    const int wid  = tid >> 6;        // 0..15

    // ---- Phase 0: q0 / delta / scale into LDS ----
    if (tid < 512) {
        float q0v = qproj[row0 * D_ + tid];
        float q1v = qproj[(row0 + 1) * D_ + tid];
        q0A[tid] = q0v;
        dA[tid]  = __builtin_amdgcn_exp2f(q1v - q0v);   // delta_d
        cA[tid]  = scale[tid];
    }
    __syncthreads();

    // ---- Phase 1: thread (sp, dq), bf16 kT ----
    const int sp  = tid & 255;        // s-pair
    const int dq  = tid >> 8;         // d-quarter
    const int dlo = dq * 128;
    const unsigned short* kb = kTb + ((size_t)(b * 512 + dlo)) * 512 + sp * 2;

    float p00 = 0.f, p10 = 0.f, p01 = 0.f, p11 = 0.f;

    unsigned int nf0 = *(const unsigned int*)(kb);
    unsigned int nf1 = *(const unsigned int*)(kb + 512);
    unsigned int nf2 = *(const unsigned int*)(kb + 1024);
    unsigned int nf3 = *(const unsigned int*)(kb + 1536);

#define SC2(KU, QV, DV, CV) do {                                              \
        float e0 = __builtin_amdgcn_exp2f((QV) + BF2X(KU));                   \
        float ra = __builtin_amdgcn_rcpf(e0 + 1.0f);                          \
        float rb = __builtin_amdgcn_rcpf(fmaf(e0, (DV), 1.0f));               \
        p00 = fmaf((CV), ra, p00); p10 = fmaf((CV), rb, p10);                 \
        float e1 = __builtin_amdgcn_exp2f((QV) + BF2Y(KU));                   \
        float rc = __builtin_amdgcn_rcpf(e1 + 1.0f);                          \
        float rd = __builtin_amdgcn_rcpf(fmaf(e1, (DV), 1.0f));               \
        p01 = fmaf((CV), rc, p01); p11 = fmaf((CV), rd, p11);                 \
    } while (0)

    for (int g = 0; g < 32; ++g) {
        unsigned int kf0 = nf0, kf1 = nf1, kf2 = nf2, kf3 = nf3;
        const unsigned short* nb = kb + (size_t)(((g + 1) & 31) * 4) * 512;
        nf0 = *(const unsigned int*)(nb);
        nf1 = *(const unsigned int*)(nb + 512);
        nf2 = *(const unsigned int*)(nb + 1024);
        nf3 = *(const unsigned int*)(nb + 1536);
        const int d0 = dlo + g * 4;
        float4 q4 = *(const float4*)&q0A[d0];
        float4 dl = *(const float4*)&dA[d0];
        float4 c4 = *(const float4*)&cA[d0];
        SC2(kf0, q4.x, dl.x, c4.x);
        SC2(kf1, q4.y, dl.y, c4.y);
        SC2(kf2, q4.z, dl.z, c4.z);
        SC2(kf3, q4.w, dl.w, c4.w);
    }
#undef SC2

    {
        float4 pq; pq.x = p00; pq.y = p10; pq.z = p01; pq.w = p11;
        pex[dq][sp] = pq;
    }
    __syncthreads();

    // ---- Phase 2: softmax over 512 s (waves 0-7), barriers block-wide ----
    float x0 = 0.f, x1 = 0.f;
    if (tid < 512) {
        const int s = tid;
        const int s2 = s >> 1;
        const bool odd = (s & 1) != 0;
        float4 r0 = pex[0][s2], r1 = pex[1][s2];
        float4 r2 = pex[2][s2], r3 = pex[3][s2];
        float pt0 = odd ? ((r0.z + r1.z) + (r2.z + r3.z))
                        : ((r0.x + r1.x) + (r2.x + r3.x));
        float pt1 = odd ? ((r0.w + r1.w) + (r2.w + r3.w))
                        : ((r0.y + r1.y) + (r2.y + r3.y));
        const int m = mask[b * S_ + s];
        x0 = m ? (-2.0f * pt0) : -1e9f;
        x1 = m ? (-2.0f * pt1) : -1e9f;
        float2 mx; mx.x = x0; mx.y = x1;
#pragma unroll
        for (int off = 32; off >= 1; off >>= 1) {
            mx.x = fmaxf(mx.x, __shfl_xor(mx.x, off));
            mx.y = fmaxf(mx.y, __shfl_xor(mx.y, off));
        }
        if (lane == 0) red2[wid] = mx;
    }
    __syncthreads();

    float e0 = 0.f, e1 = 0.f;
    if (tid < 512) {
        float2 M = red2[0];
#pragma unroll
        for (int i = 1; i < 8; ++i) {
            M.x = fmaxf(M.x, red2[i].x);
            M.y = fmaxf(M.y, red2[i].y);
        }
        e0 = __builtin_amdgcn_exp2f((x0 - M.x) * LOG2E);
        e1 = __builtin_amdgcn_exp2f((x1 - M.y) * LOG2E);
        float2 sm; sm.x = e0; sm.y = e1;
#pragma unroll
        for (int off = 32; off >= 1; off >>= 1) {
            sm.x += __shfl_xor(sm.x, off);
            sm.y += __shfl_xor(sm.y, off);
        }
        if (lane == 0) red2[8 + wid] = sm;
    }
    __syncthreads();

    if (tid < 512) {
        const int s = tid;
        float2 SS = red2[8];
#pragma unroll
        for (int i = 9; i < 16; ++i) {
            SS.x += red2[i].x;
            SS.y += red2[i].y;
        }
        const float w0 = e0 * __builtin_amdgcn_rcpf(SS.x);
        const float w1 = e1 * __builtin_amdgcn_rcpf(SS.y);
        float2 wpair; wpair.x = w0; wpair.y = w1;
        wp2[s] = wpair;
        attn[row0 * S_ + s]       = w0;
        attn[(row0 + 1) * S_ + s] = w1;
    }
    __syncthreads();

    // ---- Phase 3: context, all 16 waves ----
    const int g  = tid >> 7;          // s-group 0..7 (64 s each)
    const int v4 = tid & 127;
    const float* vb = value + ((size_t)(b * S_) + g * 64) * D_ + v4 * 4;
    float4 a0; a0.x = 0.f; a0.y = 0.f; a0.z = 0.f; a0.w = 0.f;
    float4 a1 = a0;
#pragma unroll 4
    for (int i = 0; i < 64; ++i) {
        float4 vv = *(const float4*)(vb + (size_t)i * D_);
        float2 w = wp2[g * 64 + i];
        a0.x = fmaf(w.x, vv.x, a0.x); a0.y = fmaf(w.x, vv.y, a0.y);
        a0.z = fmaf(w.x, vv.z, a0.z); a0.w = fmaf(w.x, vv.w, a0.w);
        a1.x = fmaf(w.y, vv.x, a1.x); a1.y = fmaf(w.y, vv.y, a1.y);
        a1.z = fmaf(w.y, vv.z, a1.z); a1.w = fmaf(w.y, vv.w, a1.w);
    }
    part[0][g][v4] = a0;
    part[1][g][v4] = a1;
    __syncthreads();
    if (tid < 256) {
        const int t = tid >> 7, v = tid & 127;
        float4 o; o.x = 0.f; o.y = 0.f; o.z = 0.f; o.w = 0.f;
#pragma unroll
        for (int gg = 0; gg < 8; ++gg) {
            float4 p = part[t][gg][v];
            o.x += p.x; o.y += p.y; o.z += p.z; o.w += p.w;
        }
        *(float4*)(ctx + (row0 + t) * D_ + v * 4) = o;
    }
}

extern "C" void kernel_launch(void* const* d_in, const int* in_sizes, int n_in,
                              void* d_out, int out_size, void* d_ws, size_t ws_size,
                              hipStream_t stream) {
    const float* query = (const float*)d_in[0];
    const float* value = (const float*)d_in[1];
    const int*   mask  = (const int*)  d_in[2];
    const float* W1w   = (const float*)d_in[3];
    const float* W1b   = (const float*)d_in[4];
    const float* W2w   = (const float*)d_in[5];
    const float* W2b   = (const float*)d_in[6];
    const float* scale = (const float*)d_in[7];

    float* ctx  = (float*)d_out;
    float* attn = (float*)d_out + (size_t)B_ * T_ * D_;

    float* qproj = (float*)d_ws;                       // QN f32 (1 MB)
    unsigned short* kTb = (unsigned short*)(qproj + (size_t)QN);  // KN bf16 (4 MB)

    mfma_gemm<<<576, 256, 0, stream>>>(query, value, W1w, W2w, W1b, W2b,
                                       qproj, kTb);
    fused_attn<<<256, 1024, 0, stream>>>(qproj, kTb, mask, scale, value,
                                         ctx, attn);
}